// Round 1
// baseline (90368.372 us; speedup 1.0000x reference)
//
#include <hip/hip_runtime.h>
#include <hip/hip_cooperative_groups.h>

namespace cg = cooperative_groups;

constexpr int TT = 2048;
constexpr int BB = 128;
constexpr int DD = 100;
constexpr int HH = 1024;

constexpr int NB_B = 8;             // batch groups in grid
constexpr int NB_H = 32;            // h groups in grid
constexpr int TILE_B = BB / NB_B;   // 16
constexpr int TILE_H = HH / NB_H;   // 32
constexpr int NTHREADS = 512;
constexpr int SW_STRIDE = HH + 4;   // 1028: 2*stride % 32 == 4-word spread -> 2-way (free) b128 aliasing

__global__ __launch_bounds__(NTHREADS, 1)
void rnn_persistent(const float* __restrict__ x,
                    const float* __restrict__ W_ih,
                    const float* __restrict__ b_ih,
                    const float* __restrict__ W_hh,
                    const float* __restrict__ b_hh,
                    const float* __restrict__ W_out,
                    const float* __restrict__ b_out,
                    float* __restrict__ out,
                    float* __restrict__ ws)
{
    cg::grid_group grid = cg::this_grid();

    __shared__ float sW[TILE_H][SW_STRIDE];   // 131,584 B — W_hh slice, persistent
    __shared__ float sbias[TILE_H];
    __shared__ float sPart[TILE_B][TILE_H];   // k-split partials from z==1

    const int tid = threadIdx.x;
    const int bB = blockIdx.x / NB_H;      // 0..7  batch group
    const int bH = blockIdx.x % NB_H;      // 0..31 h group
    const int hBase = bH * TILE_H;
    const int hx = tid & 15;               // 0..15
    const int by = (tid >> 4) & 15;        // 0..15
    const int z  = tid >> 8;               // 0/1, wave-uniform k-half
    const int b  = bB * TILE_B + by;

    // --- stage W_hh tile (32 x 1024) into LDS once ---
    {
        const float4* src = (const float4*)(W_hh + (size_t)hBase * HH);
        for (int i = tid; i < TILE_H * (HH / 4); i += NTHREADS) {
            int row = i >> 8;          // /256 float4s per row
            int c4  = i & 255;
            float4 v = src[row * (HH / 4) + c4];
            *(float4*)&sW[row][c4 * 4] = v;
        }
        if (tid < TILE_H) sbias[tid] = b_ih[hBase + tid] + b_hh[hBase + tid];
    }

    // --- zero h0 (ws is poisoned 0xAA before every launch) ---
    float* h0 = ws;
    float* h1 = ws + (size_t)BB * HH;
    {
        int gt = blockIdx.x * NTHREADS + tid;   // exactly BB*HH threads total
        h0[gt] = 0.0f;
    }
    grid.sync();

    const float* cur = h0;
    float* nxt = h1;

    const int h0i = hBase + hx;
    const int h1i = hBase + hx + 16;

    for (int t = 0; t < TT; ++t) {
        float a00 = 0.f, a01 = 0.f, a10 = 0.f, a11 = 0.f;

        // hidden-state dot over this thread's k-half (512 wide)
        const float4* hrow = (const float4*)(cur + (size_t)b * HH) + z * 128;
        const float4* w0 = (const float4*)&sW[hx][z * 512];
        const float4* w1 = (const float4*)&sW[hx + 16][z * 512];
        #pragma unroll 8
        for (int kk = 0; kk < 128; ++kk) {
            float4 hv = hrow[kk];
            float4 wa = w0[kk];
            float4 wb = w1[kk];
            a00 = fmaf(hv.x, wa.x, a00); a00 = fmaf(hv.y, wa.y, a00);
            a01 = fmaf(hv.z, wa.z, a01); a01 = fmaf(hv.w, wa.w, a01);
            a10 = fmaf(hv.x, wb.x, a10); a10 = fmaf(hv.y, wb.y, a10);
            a11 = fmaf(hv.z, wb.z, a11); a11 = fmaf(hv.w, wb.w, a11);
        }
        float acc0 = a00 + a01;
        float acc1 = a10 + a11;

        if (z == 1) {
            sPart[by][hx]      = acc0;
            sPart[by][hx + 16] = acc1;
        } else {
            // fused input projection x_t @ W_ih^T (D=100), z==0 half only
            const float4* xr  = (const float4*)(x + (size_t)t * BB * DD + b * DD);
            const float4* wi0 = (const float4*)(W_ih + h0i * DD);
            const float4* wi1 = (const float4*)(W_ih + h1i * DD);
            #pragma unroll
            for (int dd = 0; dd < DD / 4; ++dd) {
                float4 xv = xr[dd];
                float4 va = wi0[dd];
                float4 vb = wi1[dd];
                acc0 = fmaf(xv.x, va.x, acc0); acc0 = fmaf(xv.y, va.y, acc0);
                acc0 = fmaf(xv.z, va.z, acc0); acc0 = fmaf(xv.w, va.w, acc0);
                acc1 = fmaf(xv.x, vb.x, acc1); acc1 = fmaf(xv.y, vb.y, acc1);
                acc1 = fmaf(xv.z, vb.z, acc1); acc1 = fmaf(xv.w, vb.w, acc1);
            }
        }
        __syncthreads();
        if (z == 0) {
            float v0 = acc0 + sPart[by][hx]      + sbias[hx];
            float v1 = acc1 + sPart[by][hx + 16] + sbias[hx + 16];
            nxt[(size_t)b * HH + h0i] = tanhf(v0);
            nxt[(size_t)b * HH + h1i] = tanhf(v1);
        }
        grid.sync();
        const float* tmp = cur; cur = nxt; nxt = (float*)tmp;
    }

    // --- final projection: out[b] = tanh(h_final[b,:] . W_out[0,:] + b_out) ---
    if (blockIdx.x == 0 && tid < BB) {
        const float4* hb = (const float4*)(cur + (size_t)tid * HH);
        const float4* wo = (const float4*)W_out;
        float s0 = 0.f, s1 = 0.f;
        #pragma unroll 8
        for (int i = 0; i < HH / 4; ++i) {
            float4 hv = hb[i];
            float4 wv = wo[i];
            s0 = fmaf(hv.x, wv.x, s0); s0 = fmaf(hv.y, wv.y, s0);
            s1 = fmaf(hv.z, wv.z, s1); s1 = fmaf(hv.w, wv.w, s1);
        }
        out[tid] = tanhf(s0 + s1 + b_out[0]);
    }
}

extern "C" void kernel_launch(void* const* d_in, const int* in_sizes, int n_in,
                              void* d_out, int out_size, void* d_ws, size_t ws_size,
                              hipStream_t stream) {
    const float* x     = (const float*)d_in[0];
    const float* W_ih  = (const float*)d_in[1];
    const float* b_ih  = (const float*)d_in[2];
    const float* W_hh  = (const float*)d_in[3];
    const float* b_hh  = (const float*)d_in[4];
    const float* W_out = (const float*)d_in[5];
    const float* b_out = (const float*)d_in[6];
    float* out = (float*)d_out;
    float* ws  = (float*)d_ws;

    void* args[] = {&x, &W_ih, &b_ih, &W_hh, &b_hh, &W_out, &b_out, &out, &ws};
    hipLaunchCooperativeKernel((void*)rnn_persistent, dim3(NB_B * NB_H),
                               dim3(NTHREADS), args, 0, stream);
}

// Round 2
// 20987.410 us; speedup vs baseline: 4.3058x; 4.3058x over previous
//
#include <hip/hip_runtime.h>

constexpr int TT = 2048, BB = 128, DD = 100, HH = 1024;
constexpr int NTHREADS = 512;
constexpr int TILE_B = 16, TILE_H = 32;

using vf4 = __attribute__((ext_vector_type(4))) float;

// L3-coherent (cross-XCD) load/store: sc0 sc1 = bypass L1/L2, coherent at L3.
__device__ __forceinline__ vf4 load_f4_sc1(const void* p) {
    vf4 v;
    asm volatile("global_load_dwordx4 %0, %1, off sc0 sc1" : "=v"(v) : "v"(p) : "memory");
    return v;
}
__device__ __forceinline__ void store_f1_sc1(void* p, float v) {
    asm volatile("global_store_dword %0, %1, off sc0 sc1" :: "v"(p), "v"(v) : "memory");
}

__device__ __forceinline__ float dot4(vf4 a, vf4 b, float s) {
    s = fmaf(a.x, b.x, s); s = fmaf(a.y, b.y, s);
    s = fmaf(a.z, b.z, s); s = fmaf(a.w, b.w, s);
    return s;
}

// Barrier among the 32 blocks of batch-group g (slots[m*8+g]).
// h data is sc1 write-through, so no cache flush needed: just drain stores,
// bump own slot (relaxed agent atomic), spin until all 32 slots >= e.
// Slots start as 0xAAAAAAAA poison -> negative as int -> never false-passes.
__device__ __forceinline__ void group_barrier(unsigned* slots, int g, int m, int e, int tid) {
    asm volatile("s_waitcnt vmcnt(0)" ::: "memory");
    __syncthreads();
    if (tid == 0)
        __hip_atomic_store(&slots[(m << 3) | g], (unsigned)e,
                           __ATOMIC_RELAXED, __HIP_MEMORY_SCOPE_AGENT);
    if (tid < 64) {                 // wave 0 spins
        const int j = tid & 31;
        const bool passive = (tid >= 32);
        for (;;) {
            unsigned v = passive ? 0u
                : __hip_atomic_load(&slots[(j << 3) | g],
                                    __ATOMIC_RELAXED, __HIP_MEMORY_SCOPE_AGENT);
            bool ok = passive || ((int)v >= e);
            if (__ballot(ok) == ~0ull) break;
        }
    }
    __syncthreads();
}

__global__ __launch_bounds__(NTHREADS, 2)
void rnn_fast(const float* __restrict__ x, const float* __restrict__ W_ih,
              const float* __restrict__ b_ih, const float* __restrict__ W_hh,
              const float* __restrict__ b_hh, const float* __restrict__ W_out,
              const float* __restrict__ b_out, float* __restrict__ out,
              float* __restrict__ ws)
{
    __shared__ float sW[TILE_H][HH];       // 128 KB persistent W_hh slice
    __shared__ float sWi[TILE_H][DD];      // 12.8 KB W_ih slice
    __shared__ float sHst[TILE_B][256];    // 16 KB h stage (256-k phases)
    __shared__ float sbias[TILE_H];        // total LDS ~160,384 B

    const int tid = threadIdx.x;
    const int g = blockIdx.x & 7;          // batch group (XCD round-robin friendly)
    const int m = blockIdx.x >> 3;         // h-slice member 0..31
    const int b0 = g * TILE_B;
    const int h0r = m * TILE_H;

    const int lane = tid & 63;
    const int wave = tid >> 6;
    const int kq = lane & 15;              // in-wave 16-way k split
    const int hq = lane >> 4;              // 0..3
    const int bq = wave & 1;               // batch half
    const int hgrp = wave >> 1;            // 0..3
    const int hloc = hgrp * 8 + hq * 2;    // this thread's 2 h rows (local)
    const int srow = tid >> 6;             // stage row 0..7 (and +8)
    const int scol = tid & 63;             // stage f4 col

    float* h0 = ws;
    float* h1 = ws + BB * HH;
    unsigned* slots = (unsigned*)(ws + 2 * BB * HH);

    // --- one-time staging ---
    {
        const vf4* src = (const vf4*)(W_hh + (size_t)h0r * HH);
        vf4* dst = (vf4*)&sW[0][0];
        for (int q = tid; q < TILE_H * HH / 4; q += NTHREADS) dst[q] = src[q];
        const vf4* si = (const vf4*)(W_ih + (size_t)h0r * DD);
        vf4* di = (vf4*)&sWi[0][0];
        for (int q = tid; q < TILE_H * DD / 4; q += NTHREADS) di[q] = si[q];
        if (tid < TILE_H) sbias[tid] = b_ih[h0r + tid] + b_hh[h0r + tid];
    }
    // zero exactly the h0 slice this group will stage (disjoint cover over grid)
    store_f1_sc1(&h0[(size_t)(b0 + (tid >> 5)) * HH + m * TILE_H + (tid & 31)], 0.0f);
    __syncthreads();
    group_barrier(slots, g, m, 1, tid);

    const float* cur = h0;
    float* nxt = h1;

    for (int t = 0; t < TT; ++t) {
        // --- prefetch this step's h rows (8 x b128, sc1, FIFO-ordered) ---
        vf4 hpre[8];
        const vf4* c4 = (const vf4*)cur;
        #pragma unroll
        for (int p = 0; p < 4; ++p) {
            hpre[2 * p]     = load_f4_sc1(&c4[(size_t)(b0 + srow)     * 256 + p * 64 + scol]);
            hpre[2 * p + 1] = load_f4_sc1(&c4[(size_t)(b0 + srow + 8) * 256 + p * 64 + scol]);
        }

        float acc[8][2];
        #pragma unroll
        for (int i = 0; i < 8; i++) { acc[i][0] = 0.f; acc[i][1] = 0.f; }

        // --- d-phase: x_t @ W_ih^T, overlaps h prefetch latency ---
        const vf4* xt = (const vf4*)(x + (size_t)t * BB * DD);
        #pragma unroll
        for (int c = 0; c < 2; ++c) {
            int d = c * 64 + kq * 4;
            if (d <= DD - 4) {
                vf4 w0 = *(const vf4*)&sWi[hloc][d];
                vf4 w1 = *(const vf4*)&sWi[hloc + 1][d];
                #pragma unroll
                for (int i = 0; i < 8; i++) {
                    vf4 xv = xt[(size_t)(b0 + bq * 8 + i) * (DD / 4) + (d >> 2)];
                    acc[i][0] = dot4(xv, w0, acc[i][0]);
                    acc[i][1] = dot4(xv, w1, acc[i][1]);
                }
            }
        }

        // --- 4 phases over K=1024, h staged via LDS ---
        #pragma unroll
        for (int p = 0; p < 4; ++p) {
            if (p) __syncthreads();        // prior phase's readers done
            if (p == 0)      asm volatile("s_waitcnt vmcnt(6)" ::: "memory");
            else if (p == 1) asm volatile("s_waitcnt vmcnt(4)" ::: "memory");
            else if (p == 2) asm volatile("s_waitcnt vmcnt(2)" ::: "memory");
            else             asm volatile("s_waitcnt vmcnt(0)" ::: "memory");
            *(vf4*)&sHst[srow][scol * 4]     = hpre[2 * p];
            *(vf4*)&sHst[srow + 8][scol * 4] = hpre[2 * p + 1];
            __syncthreads();
            #pragma unroll
            for (int c = 0; c < 4; ++c) {
                int kip = c * 64 + kq * 4;
                vf4 w0 = *(const vf4*)&sW[hloc][p * 256 + kip];
                vf4 w1 = *(const vf4*)&sW[hloc + 1][p * 256 + kip];
                #pragma unroll
                for (int i = 0; i < 8; i++) {
                    vf4 hv = *(const vf4*)&sHst[bq * 8 + i][kip];
                    acc[i][0] = dot4(hv, w0, acc[i][0]);
                    acc[i][1] = dot4(hv, w1, acc[i][1]);
                }
            }
        }

        // --- in-wave k reduction (16 lanes share a tile) ---
        #pragma unroll
        for (int i = 0; i < 8; i++) {
            #pragma unroll
            for (int j = 0; j < 2; j++) {
                float v = acc[i][j];
                v += __shfl_xor(v, 1); v += __shfl_xor(v, 2);
                v += __shfl_xor(v, 4); v += __shfl_xor(v, 8);
                acc[i][j] = v;
            }
        }
        __syncthreads();                   // sHst free for reuse as red buffer
        float (*red)[TILE_H] = (float(*)[TILE_H])&sHst[0][0];
        if (kq == 0) {
            #pragma unroll
            for (int i = 0; i < 8; i++) {
                red[bq * 8 + i][hloc]     = acc[i][0];
                red[bq * 8 + i][hloc + 1] = acc[i][1];
            }
        }
        __syncthreads();
        {
            int bb = tid >> 5, hh = tid & 31;
            float v = tanhf(red[bb][hh] + sbias[hh]);
            store_f1_sc1(&nxt[(size_t)(b0 + bb) * HH + h0r + hh], v);
        }
        group_barrier(slots, g, m, t + 2, tid);
        { const float* tmp = cur; cur = nxt; nxt = (float*)tmp; }
    }

    // --- final projection: h_T ends in h0 (TT even) ---
    if (m == 0) {
        int bb = tid >> 5, part = tid & 31;
        const vf4* hp = (const vf4*)(h0 + (size_t)(b0 + bb) * HH) + part * 8;
        const vf4* wp = (const vf4*)W_out + part * 8;
        float s = 0.f;
        #pragma unroll
        for (int q = 0; q < 8; q++) s = dot4(hp[q], wp[q], s);
        s += __shfl_xor(s, 1); s += __shfl_xor(s, 2); s += __shfl_xor(s, 4);
        s += __shfl_xor(s, 8); s += __shfl_xor(s, 16);
        if (part == 0) out[b0 + bb] = tanhf(s + b_out[0]);
    }
}

extern "C" void kernel_launch(void* const* d_in, const int* in_sizes, int n_in,
                              void* d_out, int out_size, void* d_ws, size_t ws_size,
                              hipStream_t stream) {
    const float* x     = (const float*)d_in[0];
    const float* W_ih  = (const float*)d_in[1];
    const float* b_ih  = (const float*)d_in[2];
    const float* W_hh  = (const float*)d_in[3];
    const float* b_hh  = (const float*)d_in[4];
    const float* W_out = (const float*)d_in[5];
    const float* b_out = (const float*)d_in[6];
    float* out = (float*)d_out;
    float* ws  = (float*)d_ws;

    void* args[] = {&x, &W_ih, &b_ih, &W_hh, &b_hh, &W_out, &b_out, &out, &ws};
    hipLaunchCooperativeKernel((void*)rnn_fast, dim3(256), dim3(NTHREADS), args, 0, stream);
}

// Round 4
// 17918.404 us; speedup vs baseline: 5.0433x; 1.1713x over previous
//
#include <hip/hip_runtime.h>

constexpr int TT = 2048, BB = 128, DD = 100, HH = 1024;
constexpr int NTHREADS = 512;
constexpr int TILE_B = 16, TILE_H = 32;

constexpr int WST = 1032;   // W_hh row stride (ushorts): 2064 B, 16B-aligned, bank-staggered
constexpr int XST = 136;    // stage/W_ih row stride (ushorts): 272 B, 16B-aligned

typedef __attribute__((ext_vector_type(8))) short s8;
typedef __attribute__((ext_vector_type(4))) float f4;

__device__ __forceinline__ f4 load_f4_sc1(const void* p) {
    f4 v;
    asm volatile("global_load_dwordx4 %0, %1, off sc0 sc1" : "=v"(v) : "v"(p) : "memory");
    return v;
}
__device__ __forceinline__ f4 load_f4_plain(const void* p) {
    f4 v;
    asm volatile("global_load_dwordx4 %0, %1, off" : "=v"(v) : "v"(p) : "memory");
    return v;
}
__device__ __forceinline__ void store_f1_sc1(void* p, float v) {
    asm volatile("global_store_dword %0, %1, off sc0 sc1" :: "v"(p), "v"(v) : "memory");
}

// CRITICAL: ties the waitcnt into the consumer's dataflow. A bare
// `asm volatile("s_waitcnt ...")` does NOT stop the scheduler from hoisting
// VALU consumers of an asm-load's output above it (that was the round-3 NaN).
#define WAIT_PASS(n, vec) asm volatile("s_waitcnt vmcnt(" #n ")" : "+v"(vec) :: "memory")

__device__ __forceinline__ unsigned bf16_rne(float v) {
    unsigned u = __float_as_uint(v);
    return (u + 0x7FFFu + ((u >> 16) & 1u)) >> 16;
}
// v ~= hi + lo, ~16-bit mantissa coverage
__device__ __forceinline__ void split2(float v, unsigned& hi, unsigned& lo) {
    hi = bf16_rne(v);
    float fh = __uint_as_float(hi << 16);
    lo = bf16_rne(v - fh);
}

__device__ __forceinline__ float dot4(f4 a, f4 b, float s) {
    s = fmaf(a.x, b.x, s); s = fmaf(a.y, b.y, s);
    s = fmaf(a.z, b.z, s); s = fmaf(a.w, b.w, s);
    return s;
}

// Barrier among the 32 blocks sharing batch group g. h data is sc0/sc1
// (L3-coherent), so only store-drain + relaxed agent flags are needed.
__device__ __forceinline__ void group_barrier(unsigned* slots, int g, int m, int e, int tid) {
    asm volatile("s_waitcnt vmcnt(0)" ::: "memory");
    __syncthreads();
    if (tid == 0)
        __hip_atomic_store(&slots[(m << 3) | g], (unsigned)e,
                           __ATOMIC_RELAXED, __HIP_MEMORY_SCOPE_AGENT);
    if (tid < 64) {
        const int j = tid & 31;
        const bool passive = (tid >= 32);
        for (;;) {
            unsigned v = passive ? 0u
                : __hip_atomic_load(&slots[(j << 3) | g],
                                    __ATOMIC_RELAXED, __HIP_MEMORY_SCOPE_AGENT);
            bool ok = passive || ((int)v >= e);
            if (__ballot(ok) == ~0ull) break;
        }
    }
    __syncthreads();
}

__global__ __launch_bounds__(NTHREADS, 1)
void rnn_mfma(const float* __restrict__ x, const float* __restrict__ W_ih,
              const float* __restrict__ b_ih, const float* __restrict__ W_hh,
              const float* __restrict__ b_hh, const float* __restrict__ W_out,
              const float* __restrict__ b_out, float* __restrict__ out,
              float* __restrict__ ws)
{
    __shared__ __align__(16) unsigned short sWhi[TILE_H * WST];  // 66,048 B
    __shared__ __align__(16) unsigned short sWlo[TILE_H * WST];  // 66,048 B
    __shared__ __align__(16) unsigned short sIhi[TILE_H * XST];  //  8,704 B
    __shared__ __align__(16) unsigned short sIlo[TILE_H * XST];  //  8,704 B
    __shared__ __align__(16) unsigned short sAhi[TILE_B * XST];  //  4,352 B
    __shared__ __align__(16) unsigned short sAlo[TILE_B * XST];  //  4,352 B
    __shared__ float sRed[2][16][20];                            //  2,560 B
    __shared__ float sbias[TILE_H];                              // total 160,896 B

    const int tid = threadIdx.x;
    const int g = blockIdx.x & 7;          // batch group
    const int m = blockIdx.x >> 3;         // h-slice member 0..31
    const int b0 = g * TILE_B;
    const int h0r = m * TILE_H;

    float* h0p = ws;
    float* h1p = ws + BB * HH;
    unsigned* slots = (unsigned*)(ws + 2 * BB * HH);

    // ---- one-time: W_hh slice -> hi/lo LDS planes ----
    for (int i = tid; i < TILE_H * (HH / 4); i += NTHREADS) {
        int row = i >> 8, c4 = i & 255;
        f4 v = *(const f4*)(W_hh + (size_t)(h0r + row) * HH + c4 * 4);
        unsigned h_[4], l_[4];
        split2(v.x, h_[0], l_[0]); split2(v.y, h_[1], l_[1]);
        split2(v.z, h_[2], l_[2]); split2(v.w, h_[3], l_[3]);
        uint2 Hh, Hl;
        Hh.x = h_[0] | (h_[1] << 16); Hh.y = h_[2] | (h_[3] << 16);
        Hl.x = l_[0] | (l_[1] << 16); Hl.y = l_[2] | (l_[3] << 16);
        *(uint2*)&sWhi[row * WST + c4 * 4] = Hh;
        *(uint2*)&sWlo[row * WST + c4 * 4] = Hl;
    }
    // ---- one-time: W_ih slice -> hi/lo, K padded 100->128 with zeros ----
    for (int i = tid; i < TILE_H * 25; i += NTHREADS) {
        int row = i / 25, c4 = i % 25;
        f4 v = *(const f4*)(W_ih + (size_t)(h0r + row) * DD + c4 * 4);
        unsigned h_[4], l_[4];
        split2(v.x, h_[0], l_[0]); split2(v.y, h_[1], l_[1]);
        split2(v.z, h_[2], l_[2]); split2(v.w, h_[3], l_[3]);
        uint2 Hh, Hl;
        Hh.x = h_[0] | (h_[1] << 16); Hh.y = h_[2] | (h_[3] << 16);
        Hl.x = l_[0] | (l_[1] << 16); Hl.y = l_[2] | (l_[3] << 16);
        *(uint2*)&sIhi[row * XST + c4 * 4] = Hh;
        *(uint2*)&sIlo[row * XST + c4 * 4] = Hl;
    }
    for (int i = tid; i < TILE_H * (XST - DD); i += NTHREADS) {
        int row = i / (XST - DD), c = i % (XST - DD);
        sIhi[row * XST + DD + c] = 0;
        sIlo[row * XST + DD + c] = 0;
    }
    if (tid < TILE_H) sbias[tid] = b_ih[h0r + tid] + b_hh[h0r + tid];

    // zero this block's disjoint slice of h0 (ws is 0xAA-poisoned)
    store_f1_sc1(&h0p[(size_t)(b0 + (tid >> 5)) * HH + h0r + (tid & 31)], 0.0f);
    __syncthreads();
    group_barrier(slots, g, m, 1, tid);

    const float* cur = h0p;
    float* nxt = h1p;

    const int lane = tid & 63, wave = tid >> 6;
    const int cSel = wave & 3;             // K-chunk (32) within a 128-phase
    const int tSel = wave >> 2;            // N-tile (0/1)
    const int mrow = lane & 15;            // A row (batch) / B col (n)
    const int quad = lane >> 4;            // k-subgroup
    const int srow = tid >> 5;             // stage batch row 0..15
    const int scol = tid & 31;             // stage f4 col 0..31
    const unsigned aOff  = mrow * XST + cSel * 32 + quad * 8;
    const unsigned bOffW = (tSel * 16 + mrow) * WST + cSel * 32 + quad * 8;
    const unsigned bOffI = (tSel * 16 + mrow) * XST + cSel * 32 + quad * 8;
    const int ceff = scol < 25 ? scol : 24;

    for (int t = 0; t < TT; ++t) {
        // issue all prefetches (FIFO: h phases 0..7, then x) — volatile asm,
        // program order == issue order == vmcnt retire order
        f4 hpre[8];
        #pragma unroll
        for (int p = 0; p < 8; ++p)
            hpre[p] = load_f4_sc1(cur + (size_t)(b0 + srow) * HH + p * 128 + scol * 4);
        f4 xv = load_f4_plain(x + (size_t)t * BB * DD + (size_t)(b0 + srow) * DD + ceff * 4);

        // zero reduction buffer (640 floats)
        ((float*)sRed)[tid] = 0.0f;
        if (tid < 128) ((float*)sRed)[512 + tid] = 0.0f;

        f4 acc = {0.f, 0.f, 0.f, 0.f};

        #pragma unroll
        for (int p = 0; p < 8; ++p) {
            // waitcnt chained through hpre[p]'s dataflow (see WAIT_PASS)
            if      (p == 0) WAIT_PASS(8, hpre[0]);
            else if (p == 1) WAIT_PASS(7, hpre[1]);
            else if (p == 2) WAIT_PASS(6, hpre[2]);
            else if (p == 3) WAIT_PASS(5, hpre[3]);
            else if (p == 4) WAIT_PASS(4, hpre[4]);
            else if (p == 5) WAIT_PASS(3, hpre[5]);
            else if (p == 6) WAIT_PASS(2, hpre[6]);
            else             WAIT_PASS(1, hpre[7]);
            __syncthreads();               // prior phase fully consumed
            {
                f4 v = hpre[p];
                unsigned h_[4], l_[4];
                split2(v.x, h_[0], l_[0]); split2(v.y, h_[1], l_[1]);
                split2(v.z, h_[2], l_[2]); split2(v.w, h_[3], l_[3]);
                uint2 Hh, Hl;
                Hh.x = h_[0] | (h_[1] << 16); Hh.y = h_[2] | (h_[3] << 16);
                Hl.x = l_[0] | (l_[1] << 16); Hl.y = l_[2] | (l_[3] << 16);
                *(uint2*)&sAhi[srow * XST + scol * 4] = Hh;
                *(uint2*)&sAlo[srow * XST + scol * 4] = Hl;
            }
            __syncthreads();
            {
                s8 ah = *(const s8*)&sAhi[aOff];
                s8 al = *(const s8*)&sAlo[aOff];
                s8 bh = *(const s8*)&sWhi[bOffW + p * 128];
                s8 bl = *(const s8*)&sWlo[bOffW + p * 128];
                acc = __builtin_amdgcn_mfma_f32_16x16x32_bf16(ah, bh, acc, 0, 0, 0);
                acc = __builtin_amdgcn_mfma_f32_16x16x32_bf16(ah, bl, acc, 0, 0, 0);
                acc = __builtin_amdgcn_mfma_f32_16x16x32_bf16(al, bh, acc, 0, 0, 0);
            }
        }

        // ---- x phase (K-chunks 0..3 cover padded D=128) ----
        WAIT_PASS(0, xv);
        __syncthreads();
        {
            unsigned h_[4], l_[4];
            split2(xv.x, h_[0], l_[0]); split2(xv.y, h_[1], l_[1]);
            split2(xv.z, h_[2], l_[2]); split2(xv.w, h_[3], l_[3]);
            uint2 Hh, Hl;
            Hh.x = h_[0] | (h_[1] << 16); Hh.y = h_[2] | (h_[3] << 16);
            Hl.x = l_[0] | (l_[1] << 16); Hl.y = l_[2] | (l_[3] << 16);
            if (scol >= 25) { Hh.x = Hh.y = Hl.x = Hl.y = 0u; }  // zero-pad k in [100,128)
            *(uint2*)&sAhi[srow * XST + scol * 4] = Hh;
            *(uint2*)&sAlo[srow * XST + scol * 4] = Hl;
        }
        __syncthreads();
        {
            s8 ah = *(const s8*)&sAhi[aOff];
            s8 al = *(const s8*)&sAlo[aOff];
            s8 bh = *(const s8*)&sIhi[bOffI];
            s8 bl = *(const s8*)&sIlo[bOffI];
            acc = __builtin_amdgcn_mfma_f32_16x16x32_bf16(ah, bh, acc, 0, 0, 0);
            acc = __builtin_amdgcn_mfma_f32_16x16x32_bf16(ah, bl, acc, 0, 0, 0);
            acc = __builtin_amdgcn_mfma_f32_16x16x32_bf16(al, bh, acc, 0, 0, 0);
        }

        // ---- cross-wave K reduction: C/D layout col=lane&15, row=quad*4+reg ----
        #pragma unroll
        for (int r = 0; r < 4; ++r)
            atomicAdd(&sRed[tSel][quad * 4 + r][mrow], acc[r]);
        __syncthreads();
        {
            int bb = tid >> 5, hh = tid & 31;
            float vv = sRed[hh >> 4][bb][hh & 15] + sbias[hh];
            store_f1_sc1(nxt + (size_t)(b0 + bb) * HH + h0r + hh, tanhf(vv));
        }
        group_barrier(slots, g, m, t + 2, tid);
        { const float* tmp = cur; cur = nxt; nxt = (float*)tmp; }
    }

    // ---- final projection (h_T is in h0p; TT even) ----
    if (m == 0) {
        int bb = tid >> 5, part = tid & 31;
        float s = 0.f;
        #pragma unroll
        for (int q = 0; q < 8; q++) {
            f4 hv = load_f4_sc1(h0p + (size_t)(b0 + bb) * HH + (part * 8 + q) * 4);
            WAIT_PASS(0, hv);
            f4 wv = *(const f4*)(W_out + (part * 8 + q) * 4);
            s = dot4(hv, wv, s);
        }
        s += __shfl_xor(s, 1); s += __shfl_xor(s, 2); s += __shfl_xor(s, 4);
        s += __shfl_xor(s, 8); s += __shfl_xor(s, 16);
        if (part == 0) out[b0 + bb] = tanhf(s + b_out[0]);
    }
}

extern "C" void kernel_launch(void* const* d_in, const int* in_sizes, int n_in,
                              void* d_out, int out_size, void* d_ws, size_t ws_size,
                              hipStream_t stream) {
    const float* x     = (const float*)d_in[0];
    const float* W_ih  = (const float*)d_in[1];
    const float* b_ih  = (const float*)d_in[2];
    const float* W_hh  = (const float*)d_in[3];
    const float* b_hh  = (const float*)d_in[4];
    const float* W_out = (const float*)d_in[5];
    const float* b_out = (const float*)d_in[6];
    float* out = (float*)d_out;
    float* ws  = (float*)d_ws;

    void* args[] = {&x, &W_ih, &b_ih, &W_hh, &b_hh, &W_out, &b_out, &out, &ws};
    hipLaunchCooperativeKernel((void*)rnn_mfma, dim3(256), dim3(NTHREADS), args, 0, stream);
}

// Round 5
// 17728.784 us; speedup vs baseline: 5.0973x; 1.0107x over previous
//
#include <hip/hip_runtime.h>

constexpr int TT = 2048, BB = 128, DD = 100, HH = 1024;
constexpr int NTHREADS = 512;

typedef __attribute__((ext_vector_type(8))) short s8;
typedef __attribute__((ext_vector_type(4))) float f4;

__device__ __forceinline__ s8 load_s8_sc1(const void* p) {
    s8 v; asm volatile("global_load_dwordx4 %0, %1, off sc0 sc1" : "=v"(v) : "v"(p) : "memory"); return v;
}
__device__ __forceinline__ f4 load_f4_asm(const void* p) {
    f4 v; asm volatile("global_load_dwordx4 %0, %1, off" : "=v"(v) : "v"(p) : "memory"); return v;
}
__device__ __forceinline__ void store_u16_sc1(void* p, unsigned v) {
    asm volatile("global_store_short %0, %1, off sc0 sc1" :: "v"(p), "v"(v) : "memory");
}
// waitcnt chained through the consumer's dataflow (round-3/4 lesson: a bare
// waitcnt asm does NOT stop the scheduler from hoisting consumers above it)
#define WAIT2(n, a, b) asm volatile("s_waitcnt vmcnt(" #n ")" : "+v"(a), "+v"(b) :: "memory")

__device__ __forceinline__ unsigned bf16_rne(float v) {
    unsigned u = __float_as_uint(v);
    return (u + 0x7FFFu + ((u >> 16) & 1u)) >> 16;
}
__device__ __forceinline__ void split2(float v, unsigned& hi, unsigned& lo) {
    hi = bf16_rne(v);
    lo = bf16_rne(v - __uint_as_float(hi << 16));
}
__device__ __forceinline__ int flag_ld(const int* p) {
    return __hip_atomic_load(p, __ATOMIC_RELAXED, __HIP_MEMORY_SCOPE_AGENT);
}
__device__ __forceinline__ void flag_st(int* p, int v) {
    __hip_atomic_store(p, v, __ATOMIC_RELAXED, __HIP_MEMORY_SCOPE_AGENT);
}
__device__ __forceinline__ void pack8(f4 a, f4 b, s8& h8, s8& l8) {
    float vs[8] = {a.x, a.y, a.z, a.w, b.x, b.y, b.z, b.w};
    #pragma unroll
    for (int j = 0; j < 8; ++j) {
        unsigned h_, l_;
        split2(vs[j], h_, l_);
        ((unsigned short*)&h8)[j] = (unsigned short)h_;
        ((unsigned short*)&l8)[j] = (unsigned short)l_;
    }
}

#define MFMA(a, b, c) __builtin_amdgcn_mfma_f32_16x16x32_bf16((a), (b), (c), 0, 0, 0)

__global__ __launch_bounds__(NTHREADS, 1)
void rnn_pc(const float* __restrict__ x, const float* __restrict__ W_ih,
            const float* __restrict__ b_ih, const float* __restrict__ W_hh,
            const float* __restrict__ b_hh, const float* __restrict__ W_out,
            const float* __restrict__ b_out, float* __restrict__ out,
            float* __restrict__ ws)
{
    __shared__ float sRed[2 * 16 * 16 * 8];   // [tile][batch][ncol][cSel]

    const int tid = threadIdx.x;
    const int g = blockIdx.x & 7;          // batch group
    const int m = blockIdx.x >> 3;         // h-slice member 0..31
    const int b0 = g * 16;
    const int h0r = m * 32;

    const int lane = tid & 63;
    const int wave = tid >> 6;             // = cSel, 8-way K split
    const int cSel = wave;
    const bool isx = (wave >= 4);          // waves 4..7 also handle the x-projection
    const int mrow = lane & 15;
    const int quad = lane >> 4;

    unsigned short* hp = (unsigned short*)ws;
    unsigned short* hHi[2] = { hp, hp + BB * HH };
    unsigned short* hLo[2] = { hp + 2 * BB * HH, hp + 3 * BB * HH };
    int* fl = (int*)(hp + 4 * BB * HH);
    int* produced = fl;                    // [32][8], idx m*8+g
    int* consumed = fl + 256;
    int* slots    = fl + 512;

    // ---- one-time: W_hh fragments into registers (64 VGPR/lane) ----
    s8 Bh[4][2], Bl[4][2];
    #pragma unroll
    for (int p = 0; p < 4; ++p)
        #pragma unroll
        for (int tl = 0; tl < 2; ++tl) {
            const float* wr = W_hh + (size_t)(h0r + tl * 16 + mrow) * HH
                            + p * 256 + cSel * 32 + quad * 8;
            pack8(*(const f4*)wr, *(const f4*)(wr + 4), Bh[p][tl], Bl[p][tl]);
        }
    // W_ih fragments (x-waves only), K padded 100->128
    s8 Ih[2] = {}, Il[2] = {};
    const int kx = (cSel - 4) * 32 + quad * 8;
    const bool xm1 = isx && (kx <= 96);    // first f4 fully < 100
    const bool xm2 = isx && (kx <= 92);    // second f4 fully < 100
    if (isx) {
        #pragma unroll
        for (int tl = 0; tl < 2; ++tl) {
            const float* ir = W_ih + (size_t)(h0r + tl * 16 + mrow) * DD;
            f4 v1 = xm1 ? *(const f4*)(ir + kx) : f4{0.f, 0.f, 0.f, 0.f};
            f4 v2 = xm2 ? *(const f4*)(ir + kx + 4) : f4{0.f, 0.f, 0.f, 0.f};
            pack8(v1, v2, Ih[tl], Il[tl]);
        }
    }
    const float myBias = b_ih[h0r + (tid & 31)] + b_hh[h0r + (tid & 31)];

    // ---- init h0 slice (both planes) + flags, then one full-group barrier ----
    {
        int bb = tid >> 5, hh2 = tid & 31;
        store_u16_sc1(hHi[0] + (size_t)(b0 + bb) * HH + h0r + hh2, 0u);
        store_u16_sc1(hLo[0] + (size_t)(b0 + bb) * HH + h0r + hh2, 0u);
        if (tid == 0) { flag_st(&produced[m * 8 + g], 1); flag_st(&consumed[m * 8 + g], 0); }
    }
    asm volatile("s_waitcnt vmcnt(0)" ::: "memory");
    __syncthreads();
    if (tid == 0) flag_st(&slots[m * 8 + g], 1);
    for (;;) { bool ok = flag_ld(&slots[(lane & 31) * 8 + g]) >= 1; if (__ballot(ok) == ~0ull) break; }
    asm volatile("" ::: "memory");
    __syncthreads();

    int cb = 0;
    for (int t = 0; t < TT; ++t) {
        const unsigned short* cHi = hHi[cb];
        const unsigned short* cLo = hLo[cb];
        unsigned short* nHi = hHi[cb ^ 1];
        unsigned short* nLo = hLo[cb ^ 1];

        // ---- fine-grained producer check: wave cSel phase p reads member 8p+cSel ----
        {
            const int src = ((lane & 3) * 8 + cSel) * 8 + g;
            for (;;) { bool ok = flag_ld(&produced[src]) >= t + 1; if (__ballot(ok) == ~0ull) break; }
        }
        asm volatile("" ::: "memory");

        // ---- issue loads: x first (x-waves), then 8 A-plane loads; FIFO order ----
        f4 xv1{}, xv2{};
        if (isx) {
            const float* xr = x + (size_t)t * BB * DD + (size_t)(b0 + mrow) * DD;
            xv1 = load_f4_asm(xr + (xm1 ? kx : 0));
            xv2 = load_f4_asm(xr + (xm2 ? kx + 4 : 0));
        }
        s8 Ahi[4], Alo[4];
        #pragma unroll
        for (int p = 0; p < 4; ++p) {
            const size_t ao = (size_t)(b0 + mrow) * HH + p * 256 + cSel * 32 + quad * 8;
            Ahi[p] = load_s8_sc1(cHi + ao);
            Alo[p] = load_s8_sc1(cLo + ao);
        }

        f4 acc0 = {0.f, 0.f, 0.f, 0.f}, acc1 = {0.f, 0.f, 0.f, 0.f};
        WAIT2(6, Ahi[0], Alo[0]);
        acc0 = MFMA(Ahi[0], Bh[0][0], acc0); acc1 = MFMA(Ahi[0], Bh[0][1], acc1);
        acc0 = MFMA(Ahi[0], Bl[0][0], acc0); acc1 = MFMA(Ahi[0], Bl[0][1], acc1);
        acc0 = MFMA(Alo[0], Bh[0][0], acc0); acc1 = MFMA(Alo[0], Bh[0][1], acc1);
        WAIT2(4, Ahi[1], Alo[1]);
        acc0 = MFMA(Ahi[1], Bh[1][0], acc0); acc1 = MFMA(Ahi[1], Bh[1][1], acc1);
        acc0 = MFMA(Ahi[1], Bl[1][0], acc0); acc1 = MFMA(Ahi[1], Bl[1][1], acc1);
        acc0 = MFMA(Alo[1], Bh[1][0], acc0); acc1 = MFMA(Alo[1], Bh[1][1], acc1);
        WAIT2(2, Ahi[2], Alo[2]);
        acc0 = MFMA(Ahi[2], Bh[2][0], acc0); acc1 = MFMA(Ahi[2], Bh[2][1], acc1);
        acc0 = MFMA(Ahi[2], Bl[2][0], acc0); acc1 = MFMA(Ahi[2], Bl[2][1], acc1);
        acc0 = MFMA(Alo[2], Bh[2][0], acc0); acc1 = MFMA(Alo[2], Bh[2][1], acc1);
        WAIT2(0, Ahi[3], Alo[3]);
        acc0 = MFMA(Ahi[3], Bh[3][0], acc0); acc1 = MFMA(Ahi[3], Bh[3][1], acc1);
        acc0 = MFMA(Ahi[3], Bl[3][0], acc0); acc1 = MFMA(Ahi[3], Bl[3][1], acc1);
        acc0 = MFMA(Alo[3], Bh[3][0], acc0); acc1 = MFMA(Alo[3], Bh[3][1], acc1);
        if (isx) {
            WAIT2(0, xv1, xv2);
            if (!xm1) xv1 = f4{0.f, 0.f, 0.f, 0.f};
            if (!xm2) xv2 = f4{0.f, 0.f, 0.f, 0.f};
            s8 xh, xl; pack8(xv1, xv2, xh, xl);
            acc0 = MFMA(xh, Ih[0], acc0); acc1 = MFMA(xh, Ih[1], acc1);
            acc0 = MFMA(xh, Il[0], acc0); acc1 = MFMA(xh, Il[1], acc1);
            acc0 = MFMA(xl, Ih[0], acc0); acc1 = MFMA(xl, Ih[1], acc1);
        }

        // ---- reduction: C/D layout col=lane&15 (ncol), row=quad*4+r (batch) ----
        #pragma unroll
        for (int r = 0; r < 4; ++r) {
            sRed[(((quad * 4 + r) * 16 + mrow) << 3) + cSel]        = acc0[r];
            sRed[((((quad * 4 + r) + 16) * 16 + mrow) << 3) + cSel] = acc1[r];
        }
        __syncthreads();
        if (tid == 0) flag_st(&consumed[m * 8 + g], t + 1);   // our A-loads all retired
        {
            int bb = tid >> 5, hh2 = tid & 31;
            int tl = hh2 >> 4, col = hh2 & 15;
            const f4* rb = (const f4*)&sRed[((tl * 16 + bb) * 16 + col) << 3];
            f4 r0 = rb[0], r1 = rb[1];
            float sum = (((r0.x + r0.y) + (r0.z + r0.w)) + ((r1.x + r1.y) + (r1.z + r1.w))) + myBias;
            float hv = tanhf(sum);
            // buffer-reuse guard: all 32 members finished their step t-1 reads
            for (;;) { bool ok = flag_ld(&consumed[(lane & 31) * 8 + g]) >= t; if (__ballot(ok) == ~0ull) break; }
            asm volatile("" ::: "memory");
            unsigned hi_, lo_; split2(hv, hi_, lo_);
            store_u16_sc1(nHi + (size_t)(b0 + bb) * HH + h0r + hh2, hi_);
            store_u16_sc1(nLo + (size_t)(b0 + bb) * HH + h0r + hh2, lo_);
        }
        asm volatile("s_waitcnt vmcnt(0)" ::: "memory");
        __syncthreads();
        if (tid == 0) flag_st(&produced[m * 8 + g], t + 2);
        cb ^= 1;
    }

    // ---- final projection: h_TT in buffer 0 (TT even) ----
    if (m == 0) {
        for (;;) { bool ok = flag_ld(&produced[(lane & 31) * 8 + g]) >= TT + 1; if (__ballot(ok) == ~0ull) break; }
        asm volatile("" ::: "memory");
        int bb = tid >> 5, part = tid & 31;
        const unsigned short* hr = hHi[0] + (size_t)(b0 + bb) * HH;
        const unsigned short* lr = hLo[0] + (size_t)(b0 + bb) * HH;
        float s = 0.f;
        #pragma unroll
        for (int q = 0; q < 4; ++q) {
            int k = part * 32 + q * 8;
            s8 h8 = load_s8_sc1(hr + k);
            s8 l8 = load_s8_sc1(lr + k);
            WAIT2(0, h8, l8);
            #pragma unroll
            for (int j = 0; j < 8; ++j) {
                float hvj = __uint_as_float(((unsigned)((unsigned short*)&h8)[j]) << 16)
                          + __uint_as_float(((unsigned)((unsigned short*)&l8)[j]) << 16);
                s = fmaf(hvj, W_out[k + j], s);
            }
        }
        s += __shfl_xor(s, 1); s += __shfl_xor(s, 2); s += __shfl_xor(s, 4);
        s += __shfl_xor(s, 8); s += __shfl_xor(s, 16);
        if (part == 0) out[b0 + bb] = tanhf(s + b_out[0]);
    }
}

extern "C" void kernel_launch(void* const* d_in, const int* in_sizes, int n_in,
                              void* d_out, int out_size, void* d_ws, size_t ws_size,
                              hipStream_t stream) {
    const float* x     = (const float*)d_in[0];
    const float* W_ih  = (const float*)d_in[1];
    const float* b_ih  = (const float*)d_in[2];
    const float* W_hh  = (const float*)d_in[3];
    const float* b_hh  = (const float*)d_in[4];
    const float* W_out = (const float*)d_in[5];
    const float* b_out = (const float*)d_in[6];
    float* out = (float*)d_out;
    float* ws  = (float*)d_ws;

    void* args[] = {&x, &W_ih, &b_ih, &W_hh, &b_hh, &W_out, &b_out, &out, &ws};
    hipLaunchCooperativeKernel((void*)rnn_pc, dim3(256), dim3(NTHREADS), args, 0, stream);
}